// Round 3
// baseline (157.910 us; speedup 1.0000x reference)
//
#include <hip/hip_runtime.h>
#include <hip/hip_bf16.h>
#include <math.h>

typedef unsigned short u16;
typedef unsigned int u32;
typedef __bf16 bf16x8 __attribute__((ext_vector_type(8)));
typedef float f32x4 __attribute__((ext_vector_type(4)));

// B=8, T=128, S=512, E=D=512, fp32 in/out. d_out: h_tilde | wc | attn (fp32).
#define OUT_WC   524288LL
#define OUT_ATTN 1048576LL
#define C2 2.8853900817779268f   // 2*log2(e)
#define LOG2E 1.4426950408889634f
#define LAS 40                   // LDS row stride (u16): 32 + 8 pad

__device__ inline u16 f2b(float f) {
    return (u16)((__float_as_uint(f) + 0x8000u) >> 16);
}
__device__ inline float b2f(u16 v) { return __uint_as_float(((u32)v) << 16); }
__device__ inline u32 pkcvt(float x, float y) {
    __hip_bfloat162 h = __float22bfloat162_rn(make_float2(x, y));
    return *(u32*)&h;
}
__device__ inline float tanh_fast(float x) {
    return 1.f - 2.f * __builtin_amdgcn_rcpf(__builtin_amdgcn_exp2f(C2 * x) + 1.f);
}

// =============== tobf: fp32 -> bf16 pre-convert (enc|hidden|Wattn|Wout) ======
__global__ __launch_bounds__(256) void tobf(
    const float* __restrict__ enc, const float* __restrict__ hidden,
    const float* __restrict__ Wattn, const float* __restrict__ Wout,
    u16* __restrict__ dst)
{
    long long i = ((long long)blockIdx.x * 256 + threadIdx.x) * 8;
    const float* src; long long off;
    if (i < 2097152)      { src = enc;    off = i; }
    else if (i < 2621440) { src = hidden; off = i - 2097152; }
    else if (i < 3145728) { src = Wattn;  off = i - 2621440; }
    else                  { src = Wout;   off = i - 3145728; }
    float4 v0 = *(const float4*)(src + off);
    float4 v1 = *(const float4*)(src + off + 4);
    *(uint4*)(dst + i) = make_uint4(pkcvt(v0.x, v0.y), pkcvt(v0.z, v0.w),
                                    pkcvt(v1.x, v1.y), pkcvt(v1.z, v1.w));
}

// =============== proj: ept + hp + hh fused, 128x128 tiles, 192 blocks ========
// 256 thr = 4 waves, each wave owns a 64x64 quadrant (4x4 frags of 16x16x32).
// blocks 0..127:   ept[zz][kd][s] = exp2(C2 * We@enc^T)  (bf16 out)
// blocks 128..159: hp = C2*(hidden@Wh^T + battn)         (f32 out)
// blocks 160..191: hh = hidden@Wout[:,512:]^T -> d_out   (f32, in-place)
__global__ __launch_bounds__(256) void proj(
    const u16* __restrict__ hidden_bf, const u16* __restrict__ enc_bf,
    const u16* __restrict__ Wattn_bf, const float* __restrict__ battn,
    const u16* __restrict__ Wout_bf,
    float* __restrict__ hp, u16* __restrict__ ept, float* __restrict__ hh)
{
    __shared__ u16 lA[128 * LAS];   // 10KB
    __shared__ u16 lB[128 * LAS];   // 10KB
    const int tid = threadIdx.x;
    const int wvi = tid >> 6, ln = tid & 63;
    const int wm = wvi >> 1, wn = wvi & 1;      // wave -> 64x64 quadrant
    const int l16 = ln & 15, quad = ln >> 4;
    const int blk = blockIdx.x;
    int bx, by, zz = 0, lda, ldb, mode;
    const u16 *A, *B;
    if (blk < 128) {
        mode = 0;
        zz = blk >> 4; by = (blk >> 2) & 3; bx = blk & 3;
        A = Wattn_bf + 512; lda = 1024;          // rows kd, k = e
        B = enc_bf + (long long)zz * 262144; ldb = 512;  // rows s, k = e
    } else if (blk < 160) {
        mode = 1;
        int i = blk - 128; by = i >> 2; bx = i & 3;
        A = hidden_bf; lda = 512;                // rows bt, k = d
        B = Wattn_bf; ldb = 1024;                // rows kd (cols 0:512)
    } else {
        mode = 2;
        int i = blk - 160; by = i >> 2; bx = i & 3;
        A = hidden_bf; lda = 512;
        B = Wout_bf + 512; ldb = 1024;           // rows dout (cols 512:1024)
    }
    const int m0 = by * 128, n0 = bx * 128;
    const int srow = tid >> 1, skof = (tid & 1) * 16;  // 2 thr/row, 16 u16 each
    const u16* Ap = A + (long long)(m0 + srow) * lda + skof;
    const u16* Bp = B + (long long)(n0 + srow) * ldb + skof;

    f32x4 acc[4][4] = {};

    for (int k0 = 0; k0 < 512; k0 += 32) {
        uint4 av0 = *(const uint4*)(Ap + k0);
        uint4 av1 = *(const uint4*)(Ap + k0 + 8);
        uint4 bv0 = *(const uint4*)(Bp + k0);
        uint4 bv1 = *(const uint4*)(Bp + k0 + 8);
        __syncthreads();
        *(uint4*)&lA[srow * LAS + skof]     = av0;
        *(uint4*)&lA[srow * LAS + skof + 8] = av1;
        *(uint4*)&lB[srow * LAS + skof]     = bv0;
        *(uint4*)&lB[srow * LAS + skof + 8] = bv1;
        __syncthreads();
        bf16x8 af[4], bf[4];
        #pragma unroll
        for (int i = 0; i < 4; ++i)
            af[i] = *(const bf16x8*)&lA[(wm * 64 + i * 16 + l16) * LAS + quad * 8];
        #pragma unroll
        for (int j = 0; j < 4; ++j)
            bf[j] = *(const bf16x8*)&lB[(wn * 64 + j * 16 + l16) * LAS + quad * 8];
        #pragma unroll
        for (int i = 0; i < 4; ++i)
            #pragma unroll
            for (int j = 0; j < 4; ++j)
                acc[i][j] = __builtin_amdgcn_mfma_f32_16x16x32_bf16(af[i], bf[j], acc[i][j], 0, 0, 0);
    }

    #pragma unroll
    for (int i = 0; i < 4; ++i) {
        #pragma unroll
        for (int j = 0; j < 4; ++j) {
            #pragma unroll
            for (int r = 0; r < 4; ++r) {
                int m = m0 + wm * 64 + i * 16 + quad * 4 + r;
                int n = n0 + wn * 64 + j * 16 + l16;
                float v = acc[i][j][r];
                if (mode == 0)
                    ept[(long long)zz * 262144 + (long long)m * 512 + n] =
                        f2b(__builtin_amdgcn_exp2f(C2 * v));
                else if (mode == 1)
                    hp[(long long)m * 512 + n] = C2 * (v + battn[n]);
                else
                    hh[(long long)m * 512 + n] = v;
            }
        }
    }
}

// =============== wave reductions ============================================
__device__ inline float wred_sum(float v) {
    #pragma unroll
    for (int i = 32; i > 0; i >>= 1) v += __shfl_xor(v, i);
    return v;
}
__device__ inline float wred_max(float v) {
    #pragma unroll
    for (int i = 32; i > 0; i >>= 1) v = fmaxf(v, __shfl_xor(v, i));
    return v;
}

// =============== energies + masked softmax + wc (fused) ======================
// 1024 blocks (one t-row each) x 512 threads (8 waves).
// NO min-waves bound: r1/r2 showed it forces catastrophic spill. Natural
// VGPR ~50 -> 8 waves/SIMD anyway. b = bid & 7: XCD-grouped so each XCD's
// 128 blocks share ept[b]+enc[b] (~1MB) in its 4MB L2.
__device__ inline void proc8s(uint4 c, float2 hw, float* a) {
    u32 cc[4] = {c.x, c.y, c.z, c.w};
    #pragma unroll
    for (int i = 0; i < 4; ++i) {
        float xl = __uint_as_float(cc[i] << 16);
        float xh = __uint_as_float(cc[i] & 0xFFFF0000u);
        float rl = __builtin_amdgcn_rcpf(fmaf(hw.x, xl, 1.f));
        float rh = __builtin_amdgcn_rcpf(fmaf(hw.x, xh, 1.f));
        a[2*i]   = fmaf(hw.y, rl, a[2*i]);
        a[2*i+1] = fmaf(hw.y, rh, a[2*i+1]);
    }
}
__device__ inline void wcproc(uint4 c, float ap, float* acc) {
    u32 cc[4] = {c.x, c.y, c.z, c.w};
    #pragma unroll
    for (int i = 0; i < 4; ++i) {
        float el = __uint_as_float(cc[i] << 16);
        float eh = __uint_as_float(cc[i] & 0xFFFF0000u);
        acc[2*i]   = fmaf(ap, el, acc[2*i]);
        acc[2*i+1] = fmaf(ap, eh, acc[2*i+1]);
    }
}

__global__ __launch_bounds__(512) void energies(
    const float* __restrict__ maskp, const float* __restrict__ hp,
    const u16* __restrict__ ept, const float* __restrict__ Wv,
    const float* __restrict__ bvp, const u16* __restrict__ enc_bf,
    float* __restrict__ attn, float* __restrict__ wc)
{
    __shared__ __align__(8) float2 hpw[512];  // (e^{2hp}, Wv)   4KB
    __shared__ float pa[8][512];              // 16KB partials; reused for wc
    __shared__ float aL[512];                 // 2KB attn weights for wc
    __shared__ float red[8];
    const int tid = threadIdx.x;
    const int b = blockIdx.x & 7;             // XCD-grouped
    const int t = blockIdx.x >> 3;
    const long long row = (long long)(b * 128 + t) * 512;

    // ---- setup: hpw + sumWv ----
    float hv = hp[row + tid];
    float w  = Wv[tid];
    hpw[tid] = make_float2(__builtin_amdgcn_exp2f(hv), w);
    float wsum = wred_sum(w);
    if ((tid & 63) == 0) red[tid >> 6] = wsum;
    __syncthreads();                          // hpw + red visible
    float sumWv = 0.f;
    #pragma unroll
    for (int i = 0; i < 8; ++i) sumWv += red[i];

    // ---- main loop: A[s] = sum_k Wv_k / (e^{2hp}*e^{2ep} + 1) ----
    const int kg = tid >> 6, sl = tid & 63;   // kg = wave: 64 k-rows; 8 s-cols
    const int s0 = sl * 8;
    const u16* eb = ept + (long long)b * 262144 + (kg * 64) * 512 + s0;
    const float2* hq = &hpw[kg * 64];

    float a[8] = {0,0,0,0,0,0,0,0};
    uint4 c0 = *(const uint4*)(eb);
    uint4 c1 = *(const uint4*)(eb + 512);
    for (int kk = 0; kk < 62; kk += 2) {
        const u16* nb = eb + (kk + 2) * 512;
        uint4 n0 = *(const uint4*)(nb);
        uint4 n1 = *(const uint4*)(nb + 512);
        proc8s(c0, hq[kk],     a);
        proc8s(c1, hq[kk + 1], a);
        c0 = n0; c1 = n1;
    }
    proc8s(c0, hq[62], a);
    proc8s(c1, hq[63], a);

    *(float4*)&pa[kg][s0]     = make_float4(a[0], a[1], a[2], a[3]);
    *(float4*)&pa[kg][s0 + 4] = make_float4(a[4], a[5], a[6], a[7]);
    __syncthreads();

    // ---- softmax: thread owns s = tid ----
    const int s = tid;
    float A = 0.f;
    #pragma unroll
    for (int g = 0; g < 8; ++g) A += pa[g][s];    // lanes consecutive: no conflict
    float mv = maskp[(long long)b * 512 + s];
    float bv0 = bvp[0];
    float r = (bv0 + sumWv - 2.f * A) * mv; r *= mv;

    float vmax = wred_max(r);
    if ((tid & 63) == 0) red[tid >> 6] = vmax;    // safe: sumWv reads are pre-barrier
    __syncthreads();
    float mx = red[0];
    #pragma unroll
    for (int i = 1; i < 8; ++i) mx = fmaxf(mx, red[i]);

    float ex = __builtin_amdgcn_exp2f((r - mx) * LOG2E) * mv;
    float vsum = wred_sum(ex);
    __syncthreads();                              // red free again
    if ((tid & 63) == 0) red[tid >> 6] = vsum;
    __syncthreads();
    float sm = 0.f;
    #pragma unroll
    for (int i = 0; i < 8; ++i) sm += red[i];
    float at = ex * (1.f / (sm + 1e-6f));
    attn[row + s] = at;
    aL[s] = at;
    __syncthreads();                              // aL visible; pa free for reuse

    // ---- wc = attn @ enc: thread owns 8 e-cols x 64 s-rows ----
    const int eg = tid & 63, sg = tid >> 6;
    const u16* encb = enc_bf + (long long)b * 262144 + (long long)(sg * 64) * 512 + eg * 8;
    const float* aq = &aL[sg * 64];
    float acc[8] = {0,0,0,0,0,0,0,0};
    for (int j = 0; j < 64; j += 4) {
        uint4 e0 = *(const uint4*)(encb + (long long)(j + 0) * 512);
        uint4 e1 = *(const uint4*)(encb + (long long)(j + 1) * 512);
        uint4 e2 = *(const uint4*)(encb + (long long)(j + 2) * 512);
        uint4 e3 = *(const uint4*)(encb + (long long)(j + 3) * 512);
        wcproc(e0, aq[j + 0], acc);
        wcproc(e1, aq[j + 1], acc);
        wcproc(e2, aq[j + 2], acc);
        wcproc(e3, aq[j + 3], acc);
    }
    *(float4*)&pa[sg][eg * 8]     = make_float4(acc[0], acc[1], acc[2], acc[3]);
    *(float4*)&pa[sg][eg * 8 + 4] = make_float4(acc[4], acc[5], acc[6], acc[7]);
    __syncthreads();

    float wcv = 0.f;
    #pragma unroll
    for (int g = 0; g < 8; ++g) wcv += pa[g][tid];
    wc[row + tid] = wcv;
}

// =============== hout: h_tilde = tanh(wc @ Wout[:,:512]^T + hh) ==============
__global__ __launch_bounds__(256) void hout_k(
    const float* __restrict__ wc, const u16* __restrict__ Wout_bf,
    float* __restrict__ out)
{
    __shared__ u16 lA[32 * LAS];
    __shared__ u16 lB[64 * LAS];
    const int tid = threadIdx.x;
    const int wvi = tid >> 6, ln = tid & 63;
    const int l16 = ln & 15, quad = ln >> 4;
    const int msub = wvi & 1, npair = wvi >> 1;
    const int m0 = blockIdx.y * 32, n0 = blockIdx.x * 64;
    const int rowA = tid >> 3, kofA = (tid & 7) * 4;
    const int rowB = tid >> 2, kofB = (tid & 3) * 8;
    f32x4 acc0 = {0,0,0,0}, acc1 = {0,0,0,0};

    for (int k0 = 0; k0 < 512; k0 += 32) {
        float4 av = *(const float4*)(wc + (long long)(m0 + rowA) * 512 + k0 + kofA);
        uint4 bv = *(const uint4*)(Wout_bf + (long long)(n0 + rowB) * 1024 + k0 + kofB);
        __syncthreads();
        *(uint2*)&lA[rowA * LAS + kofA] = make_uint2(pkcvt(av.x, av.y), pkcvt(av.z, av.w));
        int kk = kofB ^ (((rowB >> 3) & 3) << 3);
        *(uint4*)&lB[rowB * LAS + kk] = bv;
        __syncthreads();
        bf16x8 a = *(const bf16x8*)&lA[(msub * 16 + l16) * LAS + quad * 8];
        int nr0 = npair * 32 + l16, nr1 = nr0 + 16;
        bf16x8 b0 = *(const bf16x8*)&lB[nr0 * LAS + (quad * 8 ^ (((nr0 >> 3) & 3) << 3))];
        bf16x8 b1 = *(const bf16x8*)&lB[nr1 * LAS + (quad * 8 ^ (((nr1 >> 3) & 3) << 3))];
        acc0 = __builtin_amdgcn_mfma_f32_16x16x32_bf16(a, b0, acc0, 0, 0, 0);
        acc1 = __builtin_amdgcn_mfma_f32_16x16x32_bf16(a, b1, acc1, 0, 0, 0);
    }
    #pragma unroll
    for (int j = 0; j < 2; ++j) {
        const f32x4& a = j ? acc1 : acc0;
        #pragma unroll
        for (int r = 0; r < 4; ++r) {
            int m = m0 + msub * 16 + quad * 4 + r;
            int n = n0 + npair * 32 + j * 16 + l16;
            long long idx = (long long)m * 512 + n;
            out[idx] = tanh_fast(a[r] + out[idx]);   // out[idx] holds hh
        }
    }
}

extern "C" void kernel_launch(void* const* d_in, const int* in_sizes, int n_in,
                              void* d_out, int out_size, void* d_ws, size_t ws_size,
                              hipStream_t stream)
{
    const float* hidden = (const float*)d_in[0];  // (8,128,512)
    const float* enc    = (const float*)d_in[1];  // (8,512,512)
    const float* mask   = (const float*)d_in[2];  // (8,512)
    const float* Wattn  = (const float*)d_in[3];  // (512,1024)
    const float* battn  = (const float*)d_in[4];  // (512,)
    const float* Wv     = (const float*)d_in[5];  // (512,)
    const float* bvp    = (const float*)d_in[6];  // (1,)
    const float* Wout   = (const float*)d_in[7];  // (512,1024)
    float* out = (float*)d_out;

    float* hp  = (float*)d_ws;                      // @0   2MB fp32
    u16*   ept = (u16*)((char*)d_ws + (2 << 20));   // @2M  4MB bf16 (exp2 domain)
    u16*   bfp = (u16*)((char*)d_ws + (6 << 20));   // @6M  7MB bf16 pool
    u16* enc_bf    = bfp;                // 2M elems
    u16* hidden_bf = bfp + 2097152;      // 512K
    u16* Wattn_bf  = bfp + 2621440;      // 512K
    u16* Wout_bf   = bfp + 3145728;      // 512K

    tobf<<<1792, 256, 0, stream>>>(enc, hidden, Wattn, Wout, bfp);
    proj<<<192, 256, 0, stream>>>(hidden_bf, enc_bf, Wattn_bf, battn, Wout_bf,
                                  hp, ept, out /* hh in-place */);
    energies<<<1024, 512, 0, stream>>>(mask, hp, ept, Wv, bvp, enc_bf,
                                       out + OUT_ATTN, out + OUT_WC);
    hout_k<<<dim3(8, 32, 1), 256, 0, stream>>>(out + OUT_WC, Wout_bf, out);
}

// Round 4
// 146.649 us; speedup vs baseline: 1.0768x; 1.0768x over previous
//
#include <hip/hip_runtime.h>
#include <hip/hip_bf16.h>
#include <math.h>

typedef unsigned short u16;
typedef unsigned int u32;
typedef __bf16 bf16x8 __attribute__((ext_vector_type(8)));
typedef float f32x4 __attribute__((ext_vector_type(4)));

// B=8, T=128, S=512, E=D=512, fp32 in/out. d_out: h_tilde | wc | attn (fp32).
#define OUT_WC   524288LL
#define OUT_ATTN 1048576LL
#define C2 2.8853900817779268f   // 2*log2(e)
#define LOG2E 1.4426950408889634f
#define LAS 40                   // LDS row stride (u16): 32 + 8 pad

__device__ inline u16 f2b(float f) {
    return (u16)((__float_as_uint(f) + 0x8000u) >> 16);
}
__device__ inline float b2f(u16 v) { return __uint_as_float(((u32)v) << 16); }
__device__ inline u32 pkcvt(float x, float y) {
    __hip_bfloat162 h = __float22bfloat162_rn(make_float2(x, y));
    return *(u32*)&h;
}
__device__ inline float tanh_fast(float x) {
    return 1.f - 2.f * __builtin_amdgcn_rcpf(__builtin_amdgcn_exp2f(C2 * x) + 1.f);
}

// =============== tobf: fp32 -> bf16 pre-convert (enc|hidden|Wattn|Wout) ======
__global__ __launch_bounds__(256) void tobf(
    const float* __restrict__ enc, const float* __restrict__ hidden,
    const float* __restrict__ Wattn, const float* __restrict__ Wout,
    u16* __restrict__ dst)
{
    long long i = ((long long)blockIdx.x * 256 + threadIdx.x) * 8;
    const float* src; long long off;
    if (i < 2097152)      { src = enc;    off = i; }
    else if (i < 2621440) { src = hidden; off = i - 2097152; }
    else if (i < 3145728) { src = Wattn;  off = i - 2621440; }
    else                  { src = Wout;   off = i - 3145728; }
    float4 v0 = *(const float4*)(src + off);
    float4 v1 = *(const float4*)(src + off + 4);
    *(uint4*)(dst + i) = make_uint4(pkcvt(v0.x, v0.y), pkcvt(v0.z, v0.w),
                                    pkcvt(v1.x, v1.y), pkcvt(v1.z, v1.w));
}

// =============== proj: ept + hp + hh fused, 768 blocks, 64x64 tiles ==========
// (reverted from 128x128/192-block: that grid was 0.75 blocks/CU -> 1/4 idle)
__global__ __launch_bounds__(256) void proj(
    const u16* __restrict__ hidden_bf, const u16* __restrict__ enc_bf,
    const u16* __restrict__ Wattn_bf, const float* __restrict__ battn,
    const u16* __restrict__ Wout_bf,
    float* __restrict__ hp, u16* __restrict__ ept, float* __restrict__ hh)
{
    __shared__ u16 lA[64 * LAS];
    __shared__ u16 lB[64 * LAS];
    const int tid = threadIdx.x;
    const int wvi = tid >> 6, ln = tid & 63;
    const int wm = wvi >> 1, wn = wvi & 1;
    const int l16 = ln & 15, quad = ln >> 4;
    const int blk = blockIdx.x;
    int bx, by, zz = 0, lda, ldb, mode;
    const u16 *A, *B;
    if (blk < 512) {
        mode = 0;
        zz = blk >> 6; by = (blk >> 3) & 7; bx = blk & 7;
        A = Wattn_bf + 512; lda = 1024;
        B = enc_bf + (long long)zz * 262144; ldb = 512;
    } else if (blk < 640) {
        mode = 1;
        int i = blk - 512; by = i >> 3; bx = i & 7;
        A = hidden_bf; lda = 512;
        B = Wattn_bf; ldb = 1024;
    } else {
        mode = 2;
        int i = blk - 640; by = i >> 3; bx = i & 7;
        A = hidden_bf; lda = 512;
        B = Wout_bf + 512; ldb = 1024;
    }
    const int m0 = by * 64, n0 = bx * 64;
    const int srow = tid >> 2, skof = (tid & 3) * 8;
    const u16* Ap = A + (long long)(m0 + srow) * lda + skof;
    const u16* Bp = B + (long long)(n0 + srow) * ldb + skof;

    f32x4 acc00 = {0,0,0,0}, acc01 = {0,0,0,0}, acc10 = {0,0,0,0}, acc11 = {0,0,0,0};

    for (int k0 = 0; k0 < 512; k0 += 32) {
        uint4 av = *(const uint4*)(Ap + k0);
        uint4 bv = *(const uint4*)(Bp + k0);
        __syncthreads();
        *(uint4*)&lA[srow * LAS + skof] = av;
        *(uint4*)&lB[srow * LAS + skof] = bv;
        __syncthreads();
        bf16x8 a0 = *(const bf16x8*)&lA[(wm * 32      + l16) * LAS + quad * 8];
        bf16x8 a1 = *(const bf16x8*)&lA[(wm * 32 + 16 + l16) * LAS + quad * 8];
        bf16x8 b0 = *(const bf16x8*)&lB[(wn * 32      + l16) * LAS + quad * 8];
        bf16x8 b1 = *(const bf16x8*)&lB[(wn * 32 + 16 + l16) * LAS + quad * 8];
        acc00 = __builtin_amdgcn_mfma_f32_16x16x32_bf16(a0, b0, acc00, 0, 0, 0);
        acc01 = __builtin_amdgcn_mfma_f32_16x16x32_bf16(a0, b1, acc01, 0, 0, 0);
        acc10 = __builtin_amdgcn_mfma_f32_16x16x32_bf16(a1, b0, acc10, 0, 0, 0);
        acc11 = __builtin_amdgcn_mfma_f32_16x16x32_bf16(a1, b1, acc11, 0, 0, 0);
    }

    const f32x4* accs[4] = { &acc00, &acc01, &acc10, &acc11 };
    #pragma unroll
    for (int i = 0; i < 2; ++i) {
        #pragma unroll
        for (int j = 0; j < 2; ++j) {
            const f32x4& a = *accs[i * 2 + j];
            #pragma unroll
            for (int r = 0; r < 4; ++r) {
                int m = m0 + wm * 32 + i * 16 + quad * 4 + r;
                int n = n0 + wn * 32 + j * 16 + l16;
                float v = a[r];
                if (mode == 0)
                    ept[(long long)zz * 262144 + (long long)m * 512 + n] =
                        f2b(__builtin_amdgcn_exp2f(C2 * v));
                else if (mode == 1)
                    hp[(long long)m * 512 + n] = C2 * (v + battn[n]);
                else
                    hh[(long long)m * 512 + n] = v;
            }
        }
    }
}

// =============== wave reductions ============================================
__device__ inline float wred_sum(float v) {
    #pragma unroll
    for (int i = 32; i > 0; i >>= 1) v += __shfl_xor(v, i);
    return v;
}
__device__ inline float wred_max(float v) {
    #pragma unroll
    for (int i = 32; i > 0; i >>= 1) v = fmaxf(v, __shfl_xor(v, i));
    return v;
}

// =============== energies + masked softmax + wc (fused, dual-t) ==============
// 512 blocks (b x t-pair) x 1024 threads (16 waves). 2 blocks/CU x 16 waves
// = 32 waves/CU IF VGPR <= 64 (LDS 76.3KB <= 80KB). Plain launch_bounds --
// min-waves arg caused the r1/r2 spill disasters. Dual-t amortizes bf16
// unpack over 2 t-rows (3.5 vs 4 main ops/result, 3 vs 4 in wc).
// b = bid & 7: XCD-grouped (ept[b]+enc[b] ~1MB fits the 4MB XCD L2).
__device__ inline void proc8(uint4 c, float4 hw, float* a0, float* a1) {
    u32 cc[4] = {c.x, c.y, c.z, c.w};
    #pragma unroll
    for (int i = 0; i < 4; ++i) {
        float xl = __uint_as_float(cc[i] << 16);
        float xh = __uint_as_float(cc[i] & 0xFFFF0000u);
        float rl0 = __builtin_amdgcn_rcpf(fmaf(hw.x, xl, 1.f));
        float rh0 = __builtin_amdgcn_rcpf(fmaf(hw.x, xh, 1.f));
        float rl1 = __builtin_amdgcn_rcpf(fmaf(hw.y, xl, 1.f));
        float rh1 = __builtin_amdgcn_rcpf(fmaf(hw.y, xh, 1.f));
        a0[2*i]   = fmaf(hw.z, rl0, a0[2*i]);
        a0[2*i+1] = fmaf(hw.z, rh0, a0[2*i+1]);
        a1[2*i]   = fmaf(hw.z, rl1, a1[2*i]);
        a1[2*i+1] = fmaf(hw.z, rh1, a1[2*i+1]);
    }
}
__device__ inline void wcproc2(uint4 c, float2 ap, float* acc0, float* acc1) {
    u32 cc[4] = {c.x, c.y, c.z, c.w};
    #pragma unroll
    for (int i = 0; i < 4; ++i) {
        float el = __uint_as_float(cc[i] << 16);
        float eh = __uint_as_float(cc[i] & 0xFFFF0000u);
        acc0[2*i]   = fmaf(ap.x, el, acc0[2*i]);
        acc0[2*i+1] = fmaf(ap.x, eh, acc0[2*i+1]);
        acc1[2*i]   = fmaf(ap.y, el, acc1[2*i]);
        acc1[2*i+1] = fmaf(ap.y, eh, acc1[2*i+1]);
    }
}

__global__ __launch_bounds__(1024) void energies(
    const float* __restrict__ maskp, const float* __restrict__ hp,
    const u16* __restrict__ ept, const float* __restrict__ Wv,
    const float* __restrict__ bvp, const u16* __restrict__ enc_bf,
    float* __restrict__ attn, float* __restrict__ wc)
{
    __shared__ __align__(16) float4 hpw[512];   // (e^{2hp_t0}, e^{2hp_t1}, Wv, -) 8KB
    __shared__ float pa[2][16][512];            // 64KB partials; reused for wc
    __shared__ float aL[512][2];                // 4KB attn weights for wc
    __shared__ float red[16];
    const int tid = threadIdx.x;
    const int b  = blockIdx.x & 7;              // XCD-grouped
    const int t0 = (blockIdx.x >> 3) * 2;
    const int th = tid >> 9;                    // 0: waves 0-7 (t0), 1: waves 8-15 (t0+1)
    const int k5 = tid & 511;
    const long long row0 = (long long)(b * 128 + t0) * 512;

    // ---- setup: hpw + sumWv ----
    float hv = hp[row0 + (long long)th * 512 + k5];
    float eh = __builtin_amdgcn_exp2f(hv);
    float* hpwf = (float*)hpw;
    hpwf[k5 * 4 + th] = eh;
    float w = 0.f;
    if (th == 0) { w = Wv[k5]; hpwf[k5 * 4 + 2] = w; }
    float wsum = wred_sum(w);
    if ((tid & 63) == 0) red[tid >> 6] = wsum;  // th==1 waves write 0: harmless
    __syncthreads();                            // hpw + red visible
    float sumWv = 0.f;
    #pragma unroll
    for (int i = 0; i < 16; ++i) sumWv += red[i];

    // ---- main loop: A[s] = sum_k Wv_k / (e^{2hp}*e^{2ep} + 1), both t ----
    const int kg = tid >> 6, sl = tid & 63;     // kg = wave: 32 k-rows; 8 s-cols
    const int s0 = sl * 8;
    const u16* eb = ept + (long long)b * 262144 + (kg * 32) * 512 + s0;
    const float4* hq = &hpw[kg * 32];

    float a0[8] = {0,0,0,0,0,0,0,0}, a1[8] = {0,0,0,0,0,0,0,0};
    uint4 c0 = *(const uint4*)(eb);
    uint4 c1 = *(const uint4*)(eb + 512);
    for (int kk = 0; kk < 30; kk += 2) {
        const u16* nb = eb + (kk + 2) * 512;
        uint4 n0 = *(const uint4*)(nb);
        uint4 n1 = *(const uint4*)(nb + 512);
        proc8(c0, hq[kk],     a0, a1);
        proc8(c1, hq[kk + 1], a0, a1);
        c0 = n0; c1 = n1;
    }
    proc8(c0, hq[30], a0, a1);
    proc8(c1, hq[31], a0, a1);

    *(float4*)&pa[0][kg][s0]     = make_float4(a0[0], a0[1], a0[2], a0[3]);
    *(float4*)&pa[0][kg][s0 + 4] = make_float4(a0[4], a0[5], a0[6], a0[7]);
    *(float4*)&pa[1][kg][s0]     = make_float4(a1[0], a1[1], a1[2], a1[3]);
    *(float4*)&pa[1][kg][s0 + 4] = make_float4(a1[4], a1[5], a1[6], a1[7]);
    __syncthreads();

    // ---- softmax: thread owns (t = th, s = k5); each wave is one th ----
    float A = 0.f;
    #pragma unroll
    for (int g = 0; g < 16; ++g) A += pa[th][g][k5];   // stride-1 lanes
    float mv = maskp[(long long)b * 512 + k5];
    float bv0 = bvp[0];
    float r = (bv0 + sumWv - 2.f * A) * mv; r *= mv;

    float vmax = wred_max(r);
    if ((tid & 63) == 0) red[tid >> 6] = vmax;  // sumWv reads were pre-barrier
    __syncthreads();
    float mx = red[th * 8];
    #pragma unroll
    for (int i = 1; i < 8; ++i) mx = fmaxf(mx, red[th * 8 + i]);

    float ex = __builtin_amdgcn_exp2f((r - mx) * LOG2E) * mv;
    float vsum = wred_sum(ex);
    __syncthreads();                            // mx reads done before red reuse
    if ((tid & 63) == 0) red[tid >> 6] = vsum;
    __syncthreads();
    float sm = 0.f;
    #pragma unroll
    for (int i = 0; i < 8; ++i) sm += red[th * 8 + i];
    float at = ex * (1.f / (sm + 1e-6f));
    attn[row0 + (long long)th * 512 + k5] = at;
    aL[k5][th] = at;
    __syncthreads();                            // aL visible; pa free for reuse

    // ---- wc = attn @ enc: thread owns 8 e-cols (eg) x 32 s-rows (sg) ----
    const int eg = tid & 63, sg = tid >> 6;
    const u16* encb = enc_bf + (long long)b * 262144 + (long long)(sg * 32) * 512 + eg * 8;
    const float2* aq = (const float2*)&aL[sg * 32][0];
    float acc0[8] = {0,0,0,0,0,0,0,0}, acc1[8] = {0,0,0,0,0,0,0,0};
    uint4 e0 = *(const uint4*)(encb);
    uint4 e1 = *(const uint4*)(encb + 512);
    for (int j = 0; j < 30; j += 2) {
        uint4 f0 = *(const uint4*)(encb + (long long)(j + 2) * 512);
        uint4 f1 = *(const uint4*)(encb + (long long)(j + 3) * 512);
        wcproc2(e0, aq[j],     acc0, acc1);
        wcproc2(e1, aq[j + 1], acc0, acc1);
        e0 = f0; e1 = f1;
    }
    wcproc2(e0, aq[30], acc0, acc1);
    wcproc2(e1, aq[31], acc0, acc1);

    *(float4*)&pa[0][sg][eg * 8]     = make_float4(acc0[0], acc0[1], acc0[2], acc0[3]);
    *(float4*)&pa[0][sg][eg * 8 + 4] = make_float4(acc0[4], acc0[5], acc0[6], acc0[7]);
    *(float4*)&pa[1][sg][eg * 8]     = make_float4(acc1[0], acc1[1], acc1[2], acc1[3]);
    *(float4*)&pa[1][sg][eg * 8 + 4] = make_float4(acc1[4], acc1[5], acc1[6], acc1[7]);
    __syncthreads();

    float wcv = 0.f;
    #pragma unroll
    for (int g = 0; g < 16; ++g) wcv += pa[th][g][k5];
    wc[row0 + (long long)th * 512 + k5] = wcv;
}

// =============== hout: h_tilde = tanh(wc @ Wout[:,:512]^T + hh) ==============
__global__ __launch_bounds__(256) void hout_k(
    const float* __restrict__ wc, const u16* __restrict__ Wout_bf,
    float* __restrict__ out)
{
    __shared__ u16 lA[32 * LAS];
    __shared__ u16 lB[64 * LAS];
    const int tid = threadIdx.x;
    const int wvi = tid >> 6, ln = tid & 63;
    const int l16 = ln & 15, quad = ln >> 4;
    const int msub = wvi & 1, npair = wvi >> 1;
    const int m0 = blockIdx.y * 32, n0 = blockIdx.x * 64;
    const int rowA = tid >> 3, kofA = (tid & 7) * 4;
    const int rowB = tid >> 2, kofB = (tid & 3) * 8;
    f32x4 acc0 = {0,0,0,0}, acc1 = {0,0,0,0};

    for (int k0 = 0; k0 < 512; k0 += 32) {
        float4 av = *(const float4*)(wc + (long long)(m0 + rowA) * 512 + k0 + kofA);
        uint4 bv = *(const uint4*)(Wout_bf + (long long)(n0 + rowB) * 1024 + k0 + kofB);
        __syncthreads();
        *(uint2*)&lA[rowA * LAS + kofA] = make_uint2(pkcvt(av.x, av.y), pkcvt(av.z, av.w));
        int kk = kofB ^ (((rowB >> 3) & 3) << 3);
        *(uint4*)&lB[rowB * LAS + kk] = bv;
        __syncthreads();
        bf16x8 a = *(const bf16x8*)&lA[(msub * 16 + l16) * LAS + quad * 8];
        int nr0 = npair * 32 + l16, nr1 = nr0 + 16;
        bf16x8 b0 = *(const bf16x8*)&lB[nr0 * LAS + (quad * 8 ^ (((nr0 >> 3) & 3) << 3))];
        bf16x8 b1 = *(const bf16x8*)&lB[nr1 * LAS + (quad * 8 ^ (((nr1 >> 3) & 3) << 3))];
        acc0 = __builtin_amdgcn_mfma_f32_16x16x32_bf16(a, b0, acc0, 0, 0, 0);
        acc1 = __builtin_amdgcn_mfma_f32_16x16x32_bf16(a, b1, acc1, 0, 0, 0);
    }
    #pragma unroll
    for (int j = 0; j < 2; ++j) {
        const f32x4& a = j ? acc1 : acc0;
        #pragma unroll
        for (int r = 0; r < 4; ++r) {
            int m = m0 + msub * 16 + quad * 4 + r;
            int n = n0 + npair * 32 + j * 16 + l16;
            long long idx = (long long)m * 512 + n;
            out[idx] = tanh_fast(a[r] + out[idx]);   // out[idx] holds hh
        }
    }
}

extern "C" void kernel_launch(void* const* d_in, const int* in_sizes, int n_in,
                              void* d_out, int out_size, void* d_ws, size_t ws_size,
                              hipStream_t stream)
{
    const float* hidden = (const float*)d_in[0];  // (8,128,512)
    const float* enc    = (const float*)d_in[1];  // (8,512,512)
    const float* mask   = (const float*)d_in[2];  // (8,512)
    const float* Wattn  = (const float*)d_in[3];  // (512,1024)
    const float* battn  = (const float*)d_in[4];  // (512,)
    const float* Wv     = (const float*)d_in[5];  // (512,)
    const float* bvp    = (const float*)d_in[6];  // (1,)
    const float* Wout   = (const float*)d_in[7];  // (512,1024)
    float* out = (float*)d_out;

    float* hp  = (float*)d_ws;                      // @0   2MB fp32
    u16*   ept = (u16*)((char*)d_ws + (2 << 20));   // @2M  4MB bf16 (exp2 domain)
    u16*   bfp = (u16*)((char*)d_ws + (6 << 20));   // @6M  7MB bf16 pool
    u16* enc_bf    = bfp;                // 2M elems
    u16* hidden_bf = bfp + 2097152;      // 512K
    u16* Wattn_bf  = bfp + 2621440;      // 512K
    u16* Wout_bf   = bfp + 3145728;      // 512K

    tobf<<<1792, 256, 0, stream>>>(enc, hidden, Wattn, Wout, bfp);
    proj<<<768, 256, 0, stream>>>(hidden_bf, enc_bf, Wattn_bf, battn, Wout_bf,
                                  hp, ept, out /* hh in-place */);
    energies<<<512, 1024, 0, stream>>>(mask, hp, ept, Wv, bvp, enc_bf,
                                       out + OUT_ATTN, out + OUT_WC);
    hout_k<<<dim3(8, 32, 1), 256, 0, stream>>>(out + OUT_WC, Wout_bf, out);
}